// Round 7
// baseline (483.141 us; speedup 1.0000x reference)
//
#include <hip/hip_runtime.h>
#include <hip/hip_fp16.h>
#include <math.h>

#define N_NODES 100000
#define ROWS 32              // nodes per block / bucket
#define NB 3125              // N_NODES / 32 (exact)
#define BN_EPS 1e-5f
#define PART_BLOCKS 128

// ---------------------------------------------------------------------------
__global__ void zero_misc_k(float* stats, int* gcnt) {
    int gid = blockIdx.x * blockDim.x + threadIdx.x;
    if (gid < 384) stats[gid] = 0.f;
    if (gid < NB) gcnt[gid] = 0;
}

// x fp32 -> fp16 (4 elems per thread)
__global__ void tofp16_k(const float* __restrict__ x, __half* __restrict__ xh, int n4) {
    int gid = blockIdx.x * blockDim.x + threadIdx.x;
    if (gid >= n4) return;
    float4 v = reinterpret_cast<const float4*>(x)[gid];
    union { float2 f; __half2 h[2]; } u;
    u.h[0] = __float22half2_rn(make_float2(v.x, v.y));
    u.h[1] = __float22half2_rn(make_float2(v.z, v.w));
    reinterpret_cast<float2*>(xh)[gid] = u.f;
}

// per-bucket edge histogram (bucket = dst >> 5), block-aggregated in LDS
__global__ __launch_bounds__(256) void histA_k(const int* __restrict__ ei,
                                               int* __restrict__ gcnt, int E) {
    __shared__ int cnt[NB];
    for (int i = threadIdx.x; i < NB; i += 256) cnt[i] = 0;
    __syncthreads();
    int per = (E + gridDim.x - 1) / gridDim.x;
    int s0 = blockIdx.x * per, s1 = min(E, s0 + per);
    for (int e = s0 + threadIdx.x; e < s1; e += 256)
        atomicAdd(&cnt[ei[E + e] >> 5], 1);
    __syncthreads();
    for (int i = threadIdx.x; i < NB; i += 256)
        if (cnt[i]) atomicAdd(&gcnt[i], cnt[i]);
}

// exclusive scan of NB bucket counts (single block, 13 elems/thread)
__global__ __launch_bounds__(256) void scanA_k(const int* __restrict__ gcnt,
                                               int* __restrict__ bbase,
                                               int* __restrict__ gcursor) {
    __shared__ int tmp[256];
    int t = threadIdx.x;
    int v[13];
    int s = 0;
#pragma unroll
    for (int j = 0; j < 13; ++j) {
        int idx = t * 13 + j;
        v[j] = (idx < NB) ? gcnt[idx] : 0;
        s += v[j];
    }
    tmp[t] = s;
    __syncthreads();
    for (int off = 1; off < 256; off <<= 1) {
        int a = (t >= off) ? tmp[t - off] : 0;
        __syncthreads();
        tmp[t] += a;
        __syncthreads();
    }
    int run = tmp[t] - s;
#pragma unroll
    for (int j = 0; j < 13; ++j) {
        int idx = t * 13 + j;
        if (idx < NB) { bbase[idx] = run; gcursor[idx] = run; }
        run += v[j];
    }
    if (t == 255) bbase[NB] = run;  // == E
}

// bucket-partition edges: part[] entries are (dst&31)<<20 | src, bucket-contiguous
__global__ __launch_bounds__(256) void partA_k(const int* __restrict__ ei,
                                               int* __restrict__ gcursor,
                                               int* __restrict__ part, int E) {
    __shared__ int cnt[NB];
    __shared__ int base[NB];
    for (int i = threadIdx.x; i < NB; i += 256) cnt[i] = 0;
    __syncthreads();
    int per = (E + gridDim.x - 1) / gridDim.x;
    int s0 = blockIdx.x * per, s1 = min(E, s0 + per);
    for (int e = s0 + threadIdx.x; e < s1; e += 256)
        atomicAdd(&cnt[ei[E + e] >> 5], 1);
    __syncthreads();
    for (int i = threadIdx.x; i < NB; i += 256) {
        int c = cnt[i];
        base[i] = c ? atomicAdd(&gcursor[i], c) : 0;
    }
    __syncthreads();
    for (int i = threadIdx.x; i < NB; i += 256) cnt[i] = 0;
    __syncthreads();
    for (int e = s0 + threadIdx.x; e < s1; e += 256) {
        int s = ei[e], d = ei[E + e];
        int b = d >> 5, dl = d & 31;
        int lo = atomicAdd(&cnt[b], 1);
        part[base[b] + lo] = (dl << 20) | s;
    }
}

// per-bucket LDS counting sort: part (bucket-contiguous) -> csr_src (node-ordered)
__global__ __launch_bounds__(256) void sortB_k(const int* __restrict__ part,
                                               const int* __restrict__ bbase,
                                               int* __restrict__ row_ptr,
                                               int* __restrict__ csr_src) {
    __shared__ int cnt[ROWS];
    __shared__ int cur[ROWS];
    int b = blockIdx.x;
    int t = threadIdx.x;
    int e0 = bbase[b], e1 = bbase[b + 1];
    if (t < ROWS) cnt[t] = 0;
    __syncthreads();
    for (int i = e0 + t; i < e1; i += 256) atomicAdd(&cnt[(part[i] >> 20) & 31], 1);
    __syncthreads();
    if (t < ROWS) {
        int c = cnt[t];
        int v = c;
        for (int off = 1; off < ROWS; off <<= 1) {
            int u = __shfl_up(v, off, ROWS);
            if (t >= off) v += u;
        }
        int excl = v - c;
        row_ptr[b * ROWS + t] = e0 + excl;
        cur[t] = e0 + excl;
    }
    if (t == ROWS && b == NB - 1) row_ptr[N_NODES] = e1;
    __syncthreads();
    for (int i = e0 + t; i < e1; i += 256) {
        int u = part[i];
        int dl = (u >> 20) & 31;
        int pos = atomicAdd(&cur[dl], 1);
        csr_src[pos] = u & 0xFFFFF;
    }
}

// ---------------------------------------------------------------------------
// Fused GIN layer: block = 32 dst nodes, 128 threads. Inputs are already
// activated (bnrelu applied by previous pass); gather is a pure fp16 row sum.
__global__ __launch_bounds__(128, 8) void layer_k(
    const __half* __restrict__ hin,
    const int* __restrict__ row_ptr, const int* __restrict__ csr_src,
    const float* __restrict__ epsp,
    const float* __restrict__ w1, const float* __restrict__ b1,
    const float* __restrict__ w2, const float* __restrict__ b2,
    __half* __restrict__ hout, float* __restrict__ stats) {
    __shared__ float xs[64][36];   // xs[channel][row], 32 rows + pad
    __shared__ float sred[128];

    int tid = threadIdx.x;
    int r0 = blockIdx.x * ROWS;
    if (tid < 128) sred[tid] = 0.f;

    float eps1 = 1.0f + *epsp;
    int cg = tid & 15;   // half4 slice within row
    int rr = tid >> 4;   // 0..7

    union F2H { float2 f; __half2 h[2]; };

    // Phase A: register gather, 16 lanes per node, pure fp16 sums
#pragma unroll
    for (int i = 0; i < 4; ++i) {
        int r = rr + i * 8;
        int node = r0 + r;
        const float2* selfp = reinterpret_cast<const float2*>(hin + (size_t)node * 64);
        F2H sv; sv.f = selfp[cg];
        float2 f0 = __half22float2(sv.h[0]);
        float2 f1 = __half22float2(sv.h[1]);
        float4 acc = make_float4(f0.x * eps1, f0.y * eps1, f1.x * eps1, f1.y * eps1);

        int j0 = row_ptr[node], j1 = row_ptr[node + 1];
        int j = j0;
        for (; j + 4 <= j1; j += 4) {
            int ia = csr_src[j + 0];
            int ib = csr_src[j + 1];
            int ic = csr_src[j + 2];
            int id = csr_src[j + 3];
            F2H a, b, c, d;
            a.f = reinterpret_cast<const float2*>(hin + (size_t)ia * 64)[cg];
            b.f = reinterpret_cast<const float2*>(hin + (size_t)ib * 64)[cg];
            c.f = reinterpret_cast<const float2*>(hin + (size_t)ic * 64)[cg];
            d.f = reinterpret_cast<const float2*>(hin + (size_t)id * 64)[cg];
            __half2 p0 = __hadd2(a.h[0], b.h[0]);
            __half2 p1 = __hadd2(a.h[1], b.h[1]);
            __half2 q0 = __hadd2(c.h[0], d.h[0]);
            __half2 q1 = __hadd2(c.h[1], d.h[1]);
            __half2 s0 = __hadd2(p0, q0);
            __half2 s1 = __hadd2(p1, q1);
            float2 g0 = __half22float2(s0);
            float2 g1 = __half22float2(s1);
            acc.x += g0.x; acc.y += g0.y; acc.z += g1.x; acc.w += g1.y;
        }
        for (; j < j1; ++j) {
            int sidx = csr_src[j];
            F2H u; u.f = reinterpret_cast<const float2*>(hin + (size_t)sidx * 64)[cg];
            float2 g0 = __half22float2(u.h[0]);
            float2 g1 = __half22float2(u.h[1]);
            acc.x += g0.x; acc.y += g0.y; acc.z += g1.x; acc.w += g1.y;
        }
        xs[cg * 4 + 0][r] = acc.x;
        xs[cg * 4 + 1][r] = acc.y;
        xs[cg * 4 + 2][r] = acc.z;
        xs[cg * 4 + 3][r] = acc.w;
    }
    __syncthreads();

    int tr = tid & 7, tc = tid >> 3;  // tr: row-quad 0..7, tc: col-quad 0..15
    int r = tr * 4, c = tc * 4;
    float acc[4][4];
    const float4* w14 = reinterpret_cast<const float4*>(w1);
    const float4* w24 = reinterpret_cast<const float4*>(w2);

    // ---- GEMM1: relu(xs @ W1 + b1), W streamed from global (L1 broadcast) ----
#pragma unroll
    for (int i = 0; i < 4; ++i)
#pragma unroll
        for (int j = 0; j < 4; ++j) acc[i][j] = 0.f;
#pragma unroll 4
    for (int k = 0; k < 64; ++k) {
        float4 xv = *reinterpret_cast<const float4*>(&xs[k][r]);
        float4 wv = w14[k * 16 + tc];
        float xa[4] = {xv.x, xv.y, xv.z, xv.w};
        float wa[4] = {wv.x, wv.y, wv.z, wv.w};
#pragma unroll
        for (int i = 0; i < 4; ++i)
#pragma unroll
            for (int j = 0; j < 4; ++j) acc[i][j] = fmaf(xa[i], wa[j], acc[i][j]);
    }
    {
        float4 bv = reinterpret_cast<const float4*>(b1)[tc];
        float ba[4] = {bv.x, bv.y, bv.z, bv.w};
#pragma unroll
        for (int j = 0; j < 4; ++j)
#pragma unroll
            for (int i = 0; i < 4; ++i) acc[i][j] = fmaxf(acc[i][j] + ba[j], 0.f);
    }
    __syncthreads();  // all reads of xs done

    // write h1 transposed into xs
#pragma unroll
    for (int i = 0; i < 4; ++i)
#pragma unroll
        for (int j = 0; j < 4; ++j) xs[c + j][r + i] = acc[i][j];
    __syncthreads();

    // ---- GEMM2: relu(h1 @ W2 + b2) ----
#pragma unroll
    for (int i = 0; i < 4; ++i)
#pragma unroll
        for (int j = 0; j < 4; ++j) acc[i][j] = 0.f;
#pragma unroll 4
    for (int k = 0; k < 64; ++k) {
        float4 xv = *reinterpret_cast<const float4*>(&xs[k][r]);
        float4 wv = w24[k * 16 + tc];
        float xa[4] = {xv.x, xv.y, xv.z, xv.w};
        float wa[4] = {wv.x, wv.y, wv.z, wv.w};
#pragma unroll
        for (int i = 0; i < 4; ++i)
#pragma unroll
            for (int j = 0; j < 4; ++j) acc[i][j] = fmaf(xa[i], wa[j], acc[i][j]);
    }
    {
        float4 bv = reinterpret_cast<const float4*>(b2)[tc];
        float ba[4] = {bv.x, bv.y, bv.z, bv.w};
#pragma unroll
        for (int j = 0; j < 4; ++j)
#pragma unroll
            for (int i = 0; i < 4; ++i) acc[i][j] = fmaxf(acc[i][j] + ba[j], 0.f);
    }

    // store raw h (fp16) + BN stats (fp32)
#pragma unroll
    for (int i = 0; i < 4; ++i) {
        int row = r0 + r + i;
        union { float2 f; __half2 h[2]; } u;
        u.h[0] = __float22half2_rn(make_float2(acc[i][0], acc[i][1]));
        u.h[1] = __float22half2_rn(make_float2(acc[i][2], acc[i][3]));
        *reinterpret_cast<float2*>(hout + (size_t)row * 64 + c) = u.f;
    }
#pragma unroll
    for (int j = 0; j < 4; ++j) {
        float s = 0.f, q = 0.f;
#pragma unroll
        for (int i = 0; i < 4; ++i) {
            s += acc[i][j];
            q += acc[i][j] * acc[i][j];
        }
        atomicAdd(&sred[c + j], s);
        atomicAdd(&sred[64 + c + j], q);
    }
    __syncthreads();
    if (tid < 128) atomicAdd(&stats[tid], sred[tid]);
}

// ---------------------------------------------------------------------------
// h' = relu(BN(h)) elementwise, fp16 -> fp16 (in-place safe: 1:1 mapping)
__global__ __launch_bounds__(256) void bnrelu_k(const __half* hin,
                                                const float* __restrict__ stats,
                                                const float* __restrict__ g,
                                                const float* __restrict__ bt,
                                                __half* hout) {
    __shared__ float ssc[64], sof[64];
    int tid = threadIdx.x;
    if (tid < 64) {
        float mean = stats[tid] * (1.f / N_NODES);
        float var = stats[64 + tid] * (1.f / N_NODES) - mean * mean;
        float sc = g[tid] * rsqrtf(var + BN_EPS);
        ssc[tid] = sc;
        sof[tid] = bt[tid] - mean * sc;
    }
    __syncthreads();
    int gid = blockIdx.x * 256 + tid;      // one half8 (16 B) per thread
    if (gid >= N_NODES * 8) return;
    int c0 = (gid & 7) * 8;
    union { float4 f; __half2 h[4]; } u;
    u.f = reinterpret_cast<const float4*>(hin)[gid];
#pragma unroll
    for (int q = 0; q < 4; ++q) {
        float2 v = __half22float2(u.h[q]);
        v.x = fmaxf(fmaf(v.x, ssc[c0 + 2 * q], sof[c0 + 2 * q]), 0.f);
        v.y = fmaxf(fmaf(v.y, ssc[c0 + 2 * q + 1], sof[c0 + 2 * q + 1]), 0.f);
        u.h[q] = __float22half2_rn(v);
    }
    reinterpret_cast<float4*>(hout)[gid] = u.f;
}

// ---------------------------------------------------------------------------
// out[N x 16] = h' @ wl + bl   (h' fp16, already activated)
__global__ __launch_bounds__(256) void final_k(const __half* __restrict__ hin,
                                               const float* __restrict__ wl,
                                               const float* __restrict__ bl,
                                               float* __restrict__ out) {
    __shared__ float xs[64][68];
    __shared__ float wsh[64 * 16];
    __shared__ float bsh[16];
    int tid = threadIdx.x;
    int r0 = blockIdx.x * 64;

    reinterpret_cast<float4*>(wsh)[tid] = reinterpret_cast<const float4*>(wl)[tid];
    if (tid < 16) bsh[tid] = bl[tid];

    {
        int rr = tid >> 4, cg = tid & 15;
#pragma unroll
        for (int i = 0; i < 4; ++i) {
            int r = rr + i * 16;
            float4 v = make_float4(0.f, 0.f, 0.f, 0.f);
            if (r0 + r < N_NODES) {
                union { float2 f; __half2 h[2]; } u;
                u.f = reinterpret_cast<const float2*>(hin + (size_t)(r0 + r) * 64)[cg];
                float2 f0 = __half22float2(u.h[0]);
                float2 f1 = __half22float2(u.h[1]);
                v = make_float4(f0.x, f0.y, f1.x, f1.y);
            }
            xs[cg * 4 + 0][r] = v.x;
            xs[cg * 4 + 1][r] = v.y;
            xs[cg * 4 + 2][r] = v.z;
            xs[cg * 4 + 3][r] = v.w;
        }
    }
    __syncthreads();

    int tc = tid & 3, r = tid >> 2;
    int c = tc * 4;
    float acc0 = 0.f, acc1 = 0.f, acc2 = 0.f, acc3 = 0.f;
#pragma unroll 8
    for (int k = 0; k < 64; ++k) {
        float xv = xs[k][r];
        float4 wv = *reinterpret_cast<const float4*>(&wsh[k * 16 + c]);
        acc0 = fmaf(xv, wv.x, acc0);
        acc1 = fmaf(xv, wv.y, acc1);
        acc2 = fmaf(xv, wv.z, acc2);
        acc3 = fmaf(xv, wv.w, acc3);
    }
    int row = r0 + r;
    if (row < N_NODES) {
        float4 o = make_float4(acc0 + bsh[c], acc1 + bsh[c + 1], acc2 + bsh[c + 2], acc3 + bsh[c + 3]);
        *reinterpret_cast<float4*>(out + (size_t)row * 16 + c) = o;
    }
}

// ---------------------------------------------------------------------------
extern "C" void kernel_launch(void* const* d_in, const int* in_sizes, int n_in,
                              void* d_out, int out_size, void* d_ws, size_t ws_size,
                              hipStream_t stream) {
    const float* x = (const float*)d_in[0];
    const int* ei = (const int*)d_in[1];
    const int E = in_sizes[1] / 2;

    const float* eps[3] = {(const float*)d_in[2], (const float*)d_in[9], (const float*)d_in[16]};
    const float* w1[3]  = {(const float*)d_in[3], (const float*)d_in[10], (const float*)d_in[17]};
    const float* b1[3]  = {(const float*)d_in[4], (const float*)d_in[11], (const float*)d_in[18]};
    const float* w2[3]  = {(const float*)d_in[5], (const float*)d_in[12], (const float*)d_in[19]};
    const float* b2[3]  = {(const float*)d_in[6], (const float*)d_in[13], (const float*)d_in[20]};
    const float* g[3]   = {(const float*)d_in[7], (const float*)d_in[14], (const float*)d_in[21]};
    const float* bt[3]  = {(const float*)d_in[8], (const float*)d_in[15], (const float*)d_in[22]};
    const float* wl = (const float*)d_in[23];
    const float* bl = (const float*)d_in[24];

    // workspace layout (fp16 h buffers)
    __half* xh   = (__half*)d_ws;                       // N*64 fp16
    __half* ha   = xh + (size_t)N_NODES * 64;
    __half* hb   = ha + (size_t)N_NODES * 64;
    float* stats = (float*)(hb + (size_t)N_NODES * 64);
    int* gcnt    = (int*)(stats + 384);
    int* bbase   = gcnt + NB;
    int* gcursor = bbase + (NB + 1);
    int* row_ptr = gcursor + NB;
    int* tail    = row_ptr + (N_NODES + 1);
    size_t used  = (size_t)((char*)tail - (char*)d_ws);

    int* csr_src;
    int* part;
    if (used + 2 * (size_t)E * 4 <= ws_size) {
        csr_src = tail;
        part = csr_src + E;
    } else {
        part = tail;
        csr_src = (int*)d_out;  // consumed before final_k writes d_out
    }

    const int n4 = N_NODES * 16;

    // ---- partition + CSR build + x->fp16 (once) ----
    zero_misc_k<<<(NB + 255) / 256, 256, 0, stream>>>(stats, gcnt);
    tofp16_k<<<(n4 + 255) / 256, 256, 0, stream>>>(x, xh, n4);
    histA_k<<<PART_BLOCKS, 256, 0, stream>>>(ei, gcnt, E);
    scanA_k<<<1, 256, 0, stream>>>(gcnt, bbase, gcursor);
    partA_k<<<PART_BLOCKS, 256, 0, stream>>>(ei, gcursor, part, E);
    sortB_k<<<NB, 256, 0, stream>>>(part, bbase, row_ptr, csr_src);

    const int bnblk = (N_NODES * 8 + 255) / 256;  // 3125

    // ---- 3 fused GIN layers (gather+MLP; BN+ReLU as separate pass) ----
    layer_k<<<NB, 128, 0, stream>>>(xh, row_ptr, csr_src, eps[0],
                                    w1[0], b1[0], w2[0], b2[0], ha, stats + 0);
    bnrelu_k<<<bnblk, 256, 0, stream>>>(ha, stats + 0, g[0], bt[0], ha);

    layer_k<<<NB, 128, 0, stream>>>(ha, row_ptr, csr_src, eps[1],
                                    w1[1], b1[1], w2[1], b2[1], hb, stats + 128);
    bnrelu_k<<<bnblk, 256, 0, stream>>>(hb, stats + 128, g[1], bt[1], hb);

    layer_k<<<NB, 128, 0, stream>>>(hb, row_ptr, csr_src, eps[2],
                                    w1[2], b1[2], w2[2], b2[2], ha, stats + 256);
    bnrelu_k<<<bnblk, 256, 0, stream>>>(ha, stats + 256, g[2], bt[2], ha);

    // ---- final linear (pure GEMM) ----
    final_k<<<(N_NODES + 63) / 64, 256, 0, stream>>>(ha, wl, bl, (float*)d_out);
}

// Round 8
// 441.820 us; speedup vs baseline: 1.0935x; 1.0935x over previous
//
#include <hip/hip_runtime.h>
#include <hip/hip_fp16.h>
#include <math.h>

#define N_NODES 100000
#define ROWS 32              // nodes per bucket (build kernels)
#define NB 3125              // N_NODES / 32 (exact)
#define BN_EPS 1e-5f
#define PART_BLOCKS 128

// ---------------------------------------------------------------------------
__global__ void zero_misc_k(float* stats, int* gcnt) {
    int gid = blockIdx.x * blockDim.x + threadIdx.x;
    if (gid < 384) stats[gid] = 0.f;
    if (gid < NB) gcnt[gid] = 0;
}

// x fp32 -> fp16 (4 elems per thread)
__global__ void tofp16_k(const float* __restrict__ x, __half* __restrict__ xh, int n4) {
    int gid = blockIdx.x * blockDim.x + threadIdx.x;
    if (gid >= n4) return;
    float4 v = reinterpret_cast<const float4*>(x)[gid];
    union { float2 f; __half2 h[2]; } u;
    u.h[0] = __float22half2_rn(make_float2(v.x, v.y));
    u.h[1] = __float22half2_rn(make_float2(v.z, v.w));
    reinterpret_cast<float2*>(xh)[gid] = u.f;
}

// per-bucket edge histogram (bucket = dst >> 5), block-aggregated in LDS
__global__ __launch_bounds__(256) void histA_k(const int* __restrict__ ei,
                                               int* __restrict__ gcnt, int E) {
    __shared__ int cnt[NB];
    for (int i = threadIdx.x; i < NB; i += 256) cnt[i] = 0;
    __syncthreads();
    int per = (E + gridDim.x - 1) / gridDim.x;
    int s0 = blockIdx.x * per, s1 = min(E, s0 + per);
    for (int e = s0 + threadIdx.x; e < s1; e += 256)
        atomicAdd(&cnt[ei[E + e] >> 5], 1);
    __syncthreads();
    for (int i = threadIdx.x; i < NB; i += 256)
        if (cnt[i]) atomicAdd(&gcnt[i], cnt[i]);
}

// exclusive scan of NB bucket counts (single block, 13 elems/thread)
__global__ __launch_bounds__(256) void scanA_k(const int* __restrict__ gcnt,
                                               int* __restrict__ bbase,
                                               int* __restrict__ gcursor) {
    __shared__ int tmp[256];
    int t = threadIdx.x;
    int v[13];
    int s = 0;
#pragma unroll
    for (int j = 0; j < 13; ++j) {
        int idx = t * 13 + j;
        v[j] = (idx < NB) ? gcnt[idx] : 0;
        s += v[j];
    }
    tmp[t] = s;
    __syncthreads();
    for (int off = 1; off < 256; off <<= 1) {
        int a = (t >= off) ? tmp[t - off] : 0;
        __syncthreads();
        tmp[t] += a;
        __syncthreads();
    }
    int run = tmp[t] - s;
#pragma unroll
    for (int j = 0; j < 13; ++j) {
        int idx = t * 13 + j;
        if (idx < NB) { bbase[idx] = run; gcursor[idx] = run; }
        run += v[j];
    }
    if (t == 255) bbase[NB] = run;  // == E
}

// bucket-partition edges: part[] entries are (dst&31)<<20 | src, bucket-contiguous
__global__ __launch_bounds__(256) void partA_k(const int* __restrict__ ei,
                                               int* __restrict__ gcursor,
                                               int* __restrict__ part, int E) {
    __shared__ int cnt[NB];
    __shared__ int base[NB];
    for (int i = threadIdx.x; i < NB; i += 256) cnt[i] = 0;
    __syncthreads();
    int per = (E + gridDim.x - 1) / gridDim.x;
    int s0 = blockIdx.x * per, s1 = min(E, s0 + per);
    for (int e = s0 + threadIdx.x; e < s1; e += 256)
        atomicAdd(&cnt[ei[E + e] >> 5], 1);
    __syncthreads();
    for (int i = threadIdx.x; i < NB; i += 256) {
        int c = cnt[i];
        base[i] = c ? atomicAdd(&gcursor[i], c) : 0;
    }
    __syncthreads();
    for (int i = threadIdx.x; i < NB; i += 256) cnt[i] = 0;
    __syncthreads();
    for (int e = s0 + threadIdx.x; e < s1; e += 256) {
        int s = ei[e], d = ei[E + e];
        int b = d >> 5, dl = d & 31;
        int lo = atomicAdd(&cnt[b], 1);
        part[base[b] + lo] = (dl << 20) | s;
    }
}

// per-bucket LDS counting sort: part (bucket-contiguous) -> csr_src (node-ordered)
__global__ __launch_bounds__(256) void sortB_k(const int* __restrict__ part,
                                               const int* __restrict__ bbase,
                                               int* __restrict__ row_ptr,
                                               int* __restrict__ csr_src) {
    __shared__ int cnt[ROWS];
    __shared__ int cur[ROWS];
    int b = blockIdx.x;
    int t = threadIdx.x;
    int e0 = bbase[b], e1 = bbase[b + 1];
    if (t < ROWS) cnt[t] = 0;
    __syncthreads();
    for (int i = e0 + t; i < e1; i += 256) atomicAdd(&cnt[(part[i] >> 20) & 31], 1);
    __syncthreads();
    if (t < ROWS) {
        int c = cnt[t];
        int v = c;
        for (int off = 1; off < ROWS; off <<= 1) {
            int u = __shfl_up(v, off, ROWS);
            if (t >= off) v += u;
        }
        int excl = v - c;
        row_ptr[b * ROWS + t] = e0 + excl;
        cur[t] = e0 + excl;
    }
    if (t == ROWS && b == NB - 1) row_ptr[N_NODES] = e1;
    __syncthreads();
    for (int i = e0 + t; i < e1; i += 256) {
        int u = part[i];
        int dl = (u >> 20) & 31;
        int pos = atomicAdd(&cur[dl], 1);
        csr_src[pos] = u & 0xFFFFF;
    }
}

// ---------------------------------------------------------------------------
// Pure gather: agg[n] = (1+eps)*h'[n] + sum_nbrs h'[s].  fp16 in, fp32 out.
// 16 lanes per node, 16 nodes per 256-thread block, no LDS, no barriers.
// 8-deep load pipeline per lane.
__global__ __launch_bounds__(256) void gather_k(
    const __half* __restrict__ hin, const int* __restrict__ row_ptr,
    const int* __restrict__ csr_src, const float* __restrict__ epsp,
    float* __restrict__ agg) {
    int tid = threadIdx.x;
    int lg = tid >> 4, cg = tid & 15;
    int node = blockIdx.x * 16 + lg;
    float eps1 = 1.0f + *epsp;
    union F2H { float2 f; __half2 h[2]; };

    F2H sv;
    sv.f = reinterpret_cast<const float2*>(hin + (size_t)node * 64)[cg];
    float2 f0 = __half22float2(sv.h[0]);
    float2 f1 = __half22float2(sv.h[1]);
    float4 acc = make_float4(f0.x * eps1, f0.y * eps1, f1.x * eps1, f1.y * eps1);

    int j0 = row_ptr[node], j1 = row_ptr[node + 1];
    int j = j0;
    for (; j + 8 <= j1; j += 8) {
        int idx[8];
#pragma unroll
        for (int q = 0; q < 8; ++q) idx[q] = csr_src[j + q];
        F2H u[8];
#pragma unroll
        for (int q = 0; q < 8; ++q)
            u[q].f = reinterpret_cast<const float2*>(hin + (size_t)idx[q] * 64)[cg];
#pragma unroll
        for (int q = 0; q < 8; ++q) {
            float2 g0 = __half22float2(u[q].h[0]);
            float2 g1 = __half22float2(u[q].h[1]);
            acc.x += g0.x; acc.y += g0.y; acc.z += g1.x; acc.w += g1.y;
        }
    }
    for (; j < j1; ++j) {
        F2H u;
        u.f = reinterpret_cast<const float2*>(hin + (size_t)csr_src[j] * 64)[cg];
        float2 g0 = __half22float2(u.h[0]);
        float2 g1 = __half22float2(u.h[1]);
        acc.x += g0.x; acc.y += g0.y; acc.z += g1.x; acc.w += g1.y;
    }
    reinterpret_cast<float4*>(agg + (size_t)node * 64)[cg] = acc;
}

// ---------------------------------------------------------------------------
// MLP: h = relu(relu(agg@W1+b1)@W2+b2); store fp16 + BN stats.
// 64-row tiles, 256 threads (R6's proven GEMM structure).
__global__ __launch_bounds__(256, 6) void mlp_k(
    const float* __restrict__ agg,
    const float* __restrict__ w1, const float* __restrict__ b1,
    const float* __restrict__ w2, const float* __restrict__ b2,
    __half* __restrict__ hout, float* __restrict__ stats) {
    __shared__ float xs[64][68];   // xs[channel][row]
    __shared__ float sred[128];

    int tid = threadIdx.x;
    int r0 = blockIdx.x * 64;
    if (tid < 128) sred[tid] = 0.f;

    // stage agg tile transposed (coalesced float4 reads)
    {
        int rr = tid >> 4, k4 = tid & 15;
#pragma unroll
        for (int i = 0; i < 4; ++i) {
            int r = rr + i * 16;
            int node = r0 + r;
            float4 v = make_float4(0.f, 0.f, 0.f, 0.f);
            if (node < N_NODES)
                v = reinterpret_cast<const float4*>(agg + (size_t)node * 64)[k4];
            xs[k4 * 4 + 0][r] = v.x;
            xs[k4 * 4 + 1][r] = v.y;
            xs[k4 * 4 + 2][r] = v.z;
            xs[k4 * 4 + 3][r] = v.w;
        }
    }
    __syncthreads();

    int tr = tid & 15, tc = tid >> 4;
    int r = tr * 4, c = tc * 4;
    float acc[4][4];
    const float4* w14 = reinterpret_cast<const float4*>(w1);
    const float4* w24 = reinterpret_cast<const float4*>(w2);

    // ---- GEMM1 ----
#pragma unroll
    for (int i = 0; i < 4; ++i)
#pragma unroll
        for (int j = 0; j < 4; ++j) acc[i][j] = 0.f;
#pragma unroll 4
    for (int k = 0; k < 64; ++k) {
        float4 xv = *reinterpret_cast<const float4*>(&xs[k][r]);
        float4 wv = w14[k * 16 + tc];
        float xa[4] = {xv.x, xv.y, xv.z, xv.w};
        float wa[4] = {wv.x, wv.y, wv.z, wv.w};
#pragma unroll
        for (int i = 0; i < 4; ++i)
#pragma unroll
            for (int j = 0; j < 4; ++j) acc[i][j] = fmaf(xa[i], wa[j], acc[i][j]);
    }
    {
        float4 bv = reinterpret_cast<const float4*>(b1)[tc];
        float ba[4] = {bv.x, bv.y, bv.z, bv.w};
#pragma unroll
        for (int j = 0; j < 4; ++j)
#pragma unroll
            for (int i = 0; i < 4; ++i) acc[i][j] = fmaxf(acc[i][j] + ba[j], 0.f);
    }
    __syncthreads();

    // write h1 transposed into xs
#pragma unroll
    for (int i = 0; i < 4; ++i)
#pragma unroll
        for (int j = 0; j < 4; ++j) xs[c + j][r + i] = acc[i][j];
    __syncthreads();

    // ---- GEMM2 ----
#pragma unroll
    for (int i = 0; i < 4; ++i)
#pragma unroll
        for (int j = 0; j < 4; ++j) acc[i][j] = 0.f;
#pragma unroll 4
    for (int k = 0; k < 64; ++k) {
        float4 xv = *reinterpret_cast<const float4*>(&xs[k][r]);
        float4 wv = w24[k * 16 + tc];
        float xa[4] = {xv.x, xv.y, xv.z, xv.w};
        float wa[4] = {wv.x, wv.y, wv.z, wv.w};
#pragma unroll
        for (int i = 0; i < 4; ++i)
#pragma unroll
            for (int j = 0; j < 4; ++j) acc[i][j] = fmaf(xa[i], wa[j], acc[i][j]);
    }
    {
        float4 bv = reinterpret_cast<const float4*>(b2)[tc];
        float ba[4] = {bv.x, bv.y, bv.z, bv.w};
#pragma unroll
        for (int j = 0; j < 4; ++j)
#pragma unroll
            for (int i = 0; i < 4; ++i) acc[i][j] = fmaxf(acc[i][j] + ba[j], 0.f);
    }

    // store raw h (fp16) + BN stats
#pragma unroll
    for (int i = 0; i < 4; ++i) {
        int row = r0 + r + i;
        if (row < N_NODES) {
            union { float2 f; __half2 h[2]; } u;
            u.h[0] = __float22half2_rn(make_float2(acc[i][0], acc[i][1]));
            u.h[1] = __float22half2_rn(make_float2(acc[i][2], acc[i][3]));
            *reinterpret_cast<float2*>(hout + (size_t)row * 64 + c) = u.f;
        }
    }
#pragma unroll
    for (int j = 0; j < 4; ++j) {
        float s = 0.f, q = 0.f;
#pragma unroll
        for (int i = 0; i < 4; ++i) {
            if (r0 + r + i < N_NODES) {
                s += acc[i][j];
                q += acc[i][j] * acc[i][j];
            }
        }
        atomicAdd(&sred[c + j], s);
        atomicAdd(&sred[64 + c + j], q);
    }
    __syncthreads();
    if (tid < 128) atomicAdd(&stats[tid], sred[tid]);
}

// ---------------------------------------------------------------------------
// h' = relu(BN(h)) elementwise, fp16 -> fp16
__global__ __launch_bounds__(256) void bnrelu_k(const __half* hin,
                                                const float* __restrict__ stats,
                                                const float* __restrict__ g,
                                                const float* __restrict__ bt,
                                                __half* hout) {
    __shared__ float ssc[64], sof[64];
    int tid = threadIdx.x;
    if (tid < 64) {
        float mean = stats[tid] * (1.f / N_NODES);
        float var = stats[64 + tid] * (1.f / N_NODES) - mean * mean;
        float sc = g[tid] * rsqrtf(var + BN_EPS);
        ssc[tid] = sc;
        sof[tid] = bt[tid] - mean * sc;
    }
    __syncthreads();
    int gid = blockIdx.x * 256 + tid;      // one half8 (16 B) per thread
    if (gid >= N_NODES * 8) return;
    int c0 = (gid & 7) * 8;
    union { float4 f; __half2 h[4]; } u;
    u.f = reinterpret_cast<const float4*>(hin)[gid];
#pragma unroll
    for (int q = 0; q < 4; ++q) {
        float2 v = __half22float2(u.h[q]);
        v.x = fmaxf(fmaf(v.x, ssc[c0 + 2 * q], sof[c0 + 2 * q]), 0.f);
        v.y = fmaxf(fmaf(v.y, ssc[c0 + 2 * q + 1], sof[c0 + 2 * q + 1]), 0.f);
        u.h[q] = __float22half2_rn(v);
    }
    reinterpret_cast<float4*>(hout)[gid] = u.f;
}

// ---------------------------------------------------------------------------
// out[N x 16] = h' @ wl + bl   (h' fp16, already activated)
__global__ __launch_bounds__(256) void final_k(const __half* __restrict__ hin,
                                               const float* __restrict__ wl,
                                               const float* __restrict__ bl,
                                               float* __restrict__ out) {
    __shared__ float xs[64][68];
    __shared__ float wsh[64 * 16];
    __shared__ float bsh[16];
    int tid = threadIdx.x;
    int r0 = blockIdx.x * 64;

    reinterpret_cast<float4*>(wsh)[tid] = reinterpret_cast<const float4*>(wl)[tid];
    if (tid < 16) bsh[tid] = bl[tid];

    {
        int rr = tid >> 4, cg = tid & 15;
#pragma unroll
        for (int i = 0; i < 4; ++i) {
            int r = rr + i * 16;
            float4 v = make_float4(0.f, 0.f, 0.f, 0.f);
            if (r0 + r < N_NODES) {
                union { float2 f; __half2 h[2]; } u;
                u.f = reinterpret_cast<const float2*>(hin + (size_t)(r0 + r) * 64)[cg];
                float2 f0 = __half22float2(u.h[0]);
                float2 f1 = __half22float2(u.h[1]);
                v = make_float4(f0.x, f0.y, f1.x, f1.y);
            }
            xs[cg * 4 + 0][r] = v.x;
            xs[cg * 4 + 1][r] = v.y;
            xs[cg * 4 + 2][r] = v.z;
            xs[cg * 4 + 3][r] = v.w;
        }
    }
    __syncthreads();

    int tc = tid & 3, r = tid >> 2;
    int c = tc * 4;
    float acc0 = 0.f, acc1 = 0.f, acc2 = 0.f, acc3 = 0.f;
#pragma unroll 8
    for (int k = 0; k < 64; ++k) {
        float xv = xs[k][r];
        float4 wv = *reinterpret_cast<const float4*>(&wsh[k * 16 + c]);
        acc0 = fmaf(xv, wv.x, acc0);
        acc1 = fmaf(xv, wv.y, acc1);
        acc2 = fmaf(xv, wv.z, acc2);
        acc3 = fmaf(xv, wv.w, acc3);
    }
    int row = r0 + r;
    if (row < N_NODES) {
        float4 o = make_float4(acc0 + bsh[c], acc1 + bsh[c + 1], acc2 + bsh[c + 2], acc3 + bsh[c + 3]);
        *reinterpret_cast<float4*>(out + (size_t)row * 16 + c) = o;
    }
}

// ---------------------------------------------------------------------------
extern "C" void kernel_launch(void* const* d_in, const int* in_sizes, int n_in,
                              void* d_out, int out_size, void* d_ws, size_t ws_size,
                              hipStream_t stream) {
    const float* x = (const float*)d_in[0];
    const int* ei = (const int*)d_in[1];
    const int E = in_sizes[1] / 2;

    const float* eps[3] = {(const float*)d_in[2], (const float*)d_in[9], (const float*)d_in[16]};
    const float* w1[3]  = {(const float*)d_in[3], (const float*)d_in[10], (const float*)d_in[17]};
    const float* b1[3]  = {(const float*)d_in[4], (const float*)d_in[11], (const float*)d_in[18]};
    const float* w2[3]  = {(const float*)d_in[5], (const float*)d_in[12], (const float*)d_in[19]};
    const float* b2[3]  = {(const float*)d_in[6], (const float*)d_in[13], (const float*)d_in[20]};
    const float* g[3]   = {(const float*)d_in[7], (const float*)d_in[14], (const float*)d_in[21]};
    const float* bt[3]  = {(const float*)d_in[8], (const float*)d_in[15], (const float*)d_in[22]};
    const float* wl = (const float*)d_in[23];
    const float* bl = (const float*)d_in[24];

    // workspace layout
    __half* xh   = (__half*)d_ws;                       // N*64 fp16
    __half* ha   = xh + (size_t)N_NODES * 64;
    __half* hb   = ha + (size_t)N_NODES * 64;
    float* agg   = (float*)(hb + (size_t)N_NODES * 64); // N*64 fp32
    float* stats = agg + (size_t)N_NODES * 64;
    int* gcnt    = (int*)(stats + 384);
    int* bbase   = gcnt + NB;
    int* gcursor = bbase + (NB + 1);
    int* row_ptr = gcursor + NB;
    int* tail    = row_ptr + (N_NODES + 1);
    size_t used  = (size_t)((char*)tail - (char*)d_ws);

    int* csr_src = tail;                 // E ints, persists through all layers
    int* part;                           // E ints, build-only
    if (used + 2 * (size_t)E * 4 <= ws_size) {
        part = csr_src + E;
    } else {
        // d_out (N*16 f32 = E*4 bytes) as build-only scratch; consumed by
        // sortB_k long before final_k writes d_out.
        part = (int*)d_out;
    }

    const int n4 = N_NODES * 16;

    // ---- partition + CSR build + x->fp16 (once) ----
    zero_misc_k<<<(NB + 255) / 256, 256, 0, stream>>>(stats, gcnt);
    tofp16_k<<<(n4 + 255) / 256, 256, 0, stream>>>(x, xh, n4);
    histA_k<<<PART_BLOCKS, 256, 0, stream>>>(ei, gcnt, E);
    scanA_k<<<1, 256, 0, stream>>>(gcnt, bbase, gcursor);
    partA_k<<<PART_BLOCKS, 256, 0, stream>>>(ei, gcursor, part, E);
    sortB_k<<<NB, 256, 0, stream>>>(part, bbase, row_ptr, csr_src);

    const int gthblk = N_NODES / 16;              // 6250
    const int mlpblk = (N_NODES + 63) / 64;       // 1563
    const int bnblk  = (N_NODES * 8 + 255) / 256; // 3125

    // ---- layer 0 ----
    gather_k<<<gthblk, 256, 0, stream>>>(xh, row_ptr, csr_src, eps[0], agg);
    mlp_k<<<mlpblk, 256, 0, stream>>>(agg, w1[0], b1[0], w2[0], b2[0], ha, stats + 0);
    bnrelu_k<<<bnblk, 256, 0, stream>>>(ha, stats + 0, g[0], bt[0], ha);
    // ---- layer 1 ----
    gather_k<<<gthblk, 256, 0, stream>>>(ha, row_ptr, csr_src, eps[1], agg);
    mlp_k<<<mlpblk, 256, 0, stream>>>(agg, w1[1], b1[1], w2[1], b2[1], hb, stats + 128);
    bnrelu_k<<<bnblk, 256, 0, stream>>>(hb, stats + 128, g[1], bt[1], hb);
    // ---- layer 2 ----
    gather_k<<<gthblk, 256, 0, stream>>>(hb, row_ptr, csr_src, eps[2], agg);
    mlp_k<<<mlpblk, 256, 0, stream>>>(agg, w1[2], b1[2], w2[2], b2[2], ha, stats + 256);
    bnrelu_k<<<bnblk, 256, 0, stream>>>(ha, stats + 256, g[2], bt[2], ha);

    // ---- final linear ----
    final_k<<<(N_NODES + 63) / 64, 256, 0, stream>>>(ha, wl, bl, (float*)d_out);
}

// Round 9
// 390.787 us; speedup vs baseline: 1.2363x; 1.1306x over previous
//
#include <hip/hip_runtime.h>
#include <hip/hip_fp16.h>
#include <math.h>

#define N_NODES 100000
#define ROWS 32              // nodes per bucket (build kernels)
#define NB 3125              // N_NODES / 32 (exact)
#define BN_EPS 1e-5f
#define PART_BLOCKS 128

// ---------------------------------------------------------------------------
__global__ void zero_misc_k(float* stats, int* gcnt) {
    int gid = blockIdx.x * blockDim.x + threadIdx.x;
    if (gid < 384) stats[gid] = 0.f;
    if (gid < NB) gcnt[gid] = 0;
}

// x fp32 -> fp16 (4 elems per thread)
__global__ void tofp16_k(const float* __restrict__ x, __half* __restrict__ xh, int n4) {
    int gid = blockIdx.x * blockDim.x + threadIdx.x;
    if (gid >= n4) return;
    float4 v = reinterpret_cast<const float4*>(x)[gid];
    union { float2 f; __half2 h[2]; } u;
    u.h[0] = __float22half2_rn(make_float2(v.x, v.y));
    u.h[1] = __float22half2_rn(make_float2(v.z, v.w));
    reinterpret_cast<float2*>(xh)[gid] = u.f;
}

// per-bucket edge histogram (bucket = dst >> 5), block-aggregated in LDS
__global__ __launch_bounds__(256) void histA_k(const int* __restrict__ ei,
                                               int* __restrict__ gcnt, int E) {
    __shared__ int cnt[NB];
    for (int i = threadIdx.x; i < NB; i += 256) cnt[i] = 0;
    __syncthreads();
    int per = (E + gridDim.x - 1) / gridDim.x;
    int s0 = blockIdx.x * per, s1 = min(E, s0 + per);
    for (int e = s0 + threadIdx.x; e < s1; e += 256)
        atomicAdd(&cnt[ei[E + e] >> 5], 1);
    __syncthreads();
    for (int i = threadIdx.x; i < NB; i += 256)
        if (cnt[i]) atomicAdd(&gcnt[i], cnt[i]);
}

// exclusive scan of NB bucket counts (single block, 13 elems/thread)
__global__ __launch_bounds__(256) void scanA_k(const int* __restrict__ gcnt,
                                               int* __restrict__ bbase,
                                               int* __restrict__ gcursor) {
    __shared__ int tmp[256];
    int t = threadIdx.x;
    int v[13];
    int s = 0;
#pragma unroll
    for (int j = 0; j < 13; ++j) {
        int idx = t * 13 + j;
        v[j] = (idx < NB) ? gcnt[idx] : 0;
        s += v[j];
    }
    tmp[t] = s;
    __syncthreads();
    for (int off = 1; off < 256; off <<= 1) {
        int a = (t >= off) ? tmp[t - off] : 0;
        __syncthreads();
        tmp[t] += a;
        __syncthreads();
    }
    int run = tmp[t] - s;
#pragma unroll
    for (int j = 0; j < 13; ++j) {
        int idx = t * 13 + j;
        if (idx < NB) { bbase[idx] = run; gcursor[idx] = run; }
        run += v[j];
    }
    if (t == 255) bbase[NB] = run;  // == E
}

// bucket-partition edges: part[] entries are (dst&31)<<20 | src, bucket-contiguous
__global__ __launch_bounds__(256) void partA_k(const int* __restrict__ ei,
                                               int* __restrict__ gcursor,
                                               int* __restrict__ part, int E) {
    __shared__ int cnt[NB];
    __shared__ int base[NB];
    for (int i = threadIdx.x; i < NB; i += 256) cnt[i] = 0;
    __syncthreads();
    int per = (E + gridDim.x - 1) / gridDim.x;
    int s0 = blockIdx.x * per, s1 = min(E, s0 + per);
    for (int e = s0 + threadIdx.x; e < s1; e += 256)
        atomicAdd(&cnt[ei[E + e] >> 5], 1);
    __syncthreads();
    for (int i = threadIdx.x; i < NB; i += 256) {
        int c = cnt[i];
        base[i] = c ? atomicAdd(&gcursor[i], c) : 0;
    }
    __syncthreads();
    for (int i = threadIdx.x; i < NB; i += 256) cnt[i] = 0;
    __syncthreads();
    for (int e = s0 + threadIdx.x; e < s1; e += 256) {
        int s = ei[e], d = ei[E + e];
        int b = d >> 5, dl = d & 31;
        int lo = atomicAdd(&cnt[b], 1);
        part[base[b] + lo] = (dl << 20) | s;
    }
}

// per-bucket LDS counting sort: part (bucket-contiguous) -> csr_src (node-ordered)
__global__ __launch_bounds__(256) void sortB_k(const int* __restrict__ part,
                                               const int* __restrict__ bbase,
                                               int* __restrict__ row_ptr,
                                               int* __restrict__ csr_src) {
    __shared__ int cnt[ROWS];
    __shared__ int cur[ROWS];
    int b = blockIdx.x;
    int t = threadIdx.x;
    int e0 = bbase[b], e1 = bbase[b + 1];
    if (t < ROWS) cnt[t] = 0;
    __syncthreads();
    for (int i = e0 + t; i < e1; i += 256) atomicAdd(&cnt[(part[i] >> 20) & 31], 1);
    __syncthreads();
    if (t < ROWS) {
        int c = cnt[t];
        int v = c;
        for (int off = 1; off < ROWS; off <<= 1) {
            int u = __shfl_up(v, off, ROWS);
            if (t >= off) v += u;
        }
        int excl = v - c;
        row_ptr[b * ROWS + t] = e0 + excl;
        cur[t] = e0 + excl;
    }
    if (t == ROWS && b == NB - 1) row_ptr[N_NODES] = e1;
    __syncthreads();
    for (int i = e0 + t; i < e1; i += 256) {
        int u = part[i];
        int dl = (u >> 20) & 31;
        int pos = atomicAdd(&cur[dl], 1);
        csr_src[pos] = u & 0xFFFFF;
    }
}

// ---------------------------------------------------------------------------
// Pure gather: agg[n] = (1+eps)*h'[n] + sum_nbrs h'[s].  fp16 in, fp32 out.
// 16 lanes per node, 16 nodes per 256-thread block, no LDS, no barriers.
__global__ __launch_bounds__(256) void gather_k(
    const __half* __restrict__ hin, const int* __restrict__ row_ptr,
    const int* __restrict__ csr_src, const float* __restrict__ epsp,
    float* __restrict__ agg) {
    int tid = threadIdx.x;
    int lg = tid >> 4, cg = tid & 15;
    int node = blockIdx.x * 16 + lg;
    float eps1 = 1.0f + *epsp;
    union F2H { float2 f; __half2 h[2]; };

    F2H sv;
    sv.f = reinterpret_cast<const float2*>(hin + (size_t)node * 64)[cg];
    float2 f0 = __half22float2(sv.h[0]);
    float2 f1 = __half22float2(sv.h[1]);
    float4 acc = make_float4(f0.x * eps1, f0.y * eps1, f1.x * eps1, f1.y * eps1);

    int j0 = row_ptr[node], j1 = row_ptr[node + 1];
    int j = j0;
    for (; j + 8 <= j1; j += 8) {
        int idx[8];
#pragma unroll
        for (int q = 0; q < 8; ++q) idx[q] = csr_src[j + q];
        F2H u[8];
#pragma unroll
        for (int q = 0; q < 8; ++q)
            u[q].f = reinterpret_cast<const float2*>(hin + (size_t)idx[q] * 64)[cg];
#pragma unroll
        for (int q = 0; q < 8; ++q) {
            float2 g0 = __half22float2(u[q].h[0]);
            float2 g1 = __half22float2(u[q].h[1]);
            acc.x += g0.x; acc.y += g0.y; acc.z += g1.x; acc.w += g1.y;
        }
    }
    for (; j < j1; ++j) {
        F2H u;
        u.f = reinterpret_cast<const float2*>(hin + (size_t)csr_src[j] * 64)[cg];
        float2 g0 = __half22float2(u.h[0]);
        float2 g1 = __half22float2(u.h[1]);
        acc.x += g0.x; acc.y += g0.y; acc.z += g1.x; acc.w += g1.y;
    }
    reinterpret_cast<float4*>(agg + (size_t)node * 64)[cg] = acc;
}

// ---------------------------------------------------------------------------
// MLP: h = relu(relu(agg@W1+b1)@W2+b2); store fp16 + BN stats.
// 64-row tiles, 256 threads; W1/W2 LDS-staged (hot-swap) to kill the per-k
// global-load latency that made the streamed version 85 us.
__global__ __launch_bounds__(256) void mlp_k(
    const float* __restrict__ agg,
    const float* __restrict__ w1, const float* __restrict__ b1,
    const float* __restrict__ w2, const float* __restrict__ b2,
    __half* __restrict__ hout, float* __restrict__ stats) {
    __shared__ float xs[64][68];   // xs[channel][row]
    __shared__ float wsh[4096];
    __shared__ float bsh[64];
    __shared__ float sred[128];

    int tid = threadIdx.x;
    int r0 = blockIdx.x * 64;
    if (tid < 128) sred[tid] = 0.f;

    // stage W1 + b1
    const float4* w14 = reinterpret_cast<const float4*>(w1);
    float4* wsh4 = reinterpret_cast<float4*>(wsh);
#pragma unroll
    for (int i = 0; i < 4; ++i) wsh4[tid + i * 256] = w14[tid + i * 256];
    if (tid < 64) bsh[tid] = b1[tid];

    // stage agg tile transposed (coalesced float4 reads)
    {
        int rr = tid >> 4, k4 = tid & 15;
#pragma unroll
        for (int i = 0; i < 4; ++i) {
            int r = rr + i * 16;
            int node = r0 + r;
            float4 v = make_float4(0.f, 0.f, 0.f, 0.f);
            if (node < N_NODES)
                v = reinterpret_cast<const float4*>(agg + (size_t)node * 64)[k4];
            xs[k4 * 4 + 0][r] = v.x;
            xs[k4 * 4 + 1][r] = v.y;
            xs[k4 * 4 + 2][r] = v.z;
            xs[k4 * 4 + 3][r] = v.w;
        }
    }
    __syncthreads();

    int tr = tid & 15, tc = tid >> 4;
    int r = tr * 4, c = tc * 4;
    float acc[4][4];

    // ---- GEMM1: relu(xs @ W1 + b1) ----
#pragma unroll
    for (int i = 0; i < 4; ++i)
#pragma unroll
        for (int j = 0; j < 4; ++j) acc[i][j] = 0.f;
#pragma unroll 8
    for (int k = 0; k < 64; ++k) {
        float4 xv = *reinterpret_cast<const float4*>(&xs[k][r]);
        float4 wv = *reinterpret_cast<const float4*>(&wsh[k * 64 + c]);
        float xa[4] = {xv.x, xv.y, xv.z, xv.w};
        float wa[4] = {wv.x, wv.y, wv.z, wv.w};
#pragma unroll
        for (int i = 0; i < 4; ++i)
#pragma unroll
            for (int j = 0; j < 4; ++j) acc[i][j] = fmaf(xa[i], wa[j], acc[i][j]);
    }
    {
        float bj0 = bsh[c + 0], bj1 = bsh[c + 1], bj2 = bsh[c + 2], bj3 = bsh[c + 3];
#pragma unroll
        for (int i = 0; i < 4; ++i) {
            acc[i][0] = fmaxf(acc[i][0] + bj0, 0.f);
            acc[i][1] = fmaxf(acc[i][1] + bj1, 0.f);
            acc[i][2] = fmaxf(acc[i][2] + bj2, 0.f);
            acc[i][3] = fmaxf(acc[i][3] + bj3, 0.f);
        }
    }
    __syncthreads();  // all reads of xs/wsh done

    // write h1 transposed into xs; hot-swap W2/b2
#pragma unroll
    for (int i = 0; i < 4; ++i)
#pragma unroll
        for (int j = 0; j < 4; ++j) xs[c + j][r + i] = acc[i][j];
    const float4* w24 = reinterpret_cast<const float4*>(w2);
#pragma unroll
    for (int i = 0; i < 4; ++i) wsh4[tid + i * 256] = w24[tid + i * 256];
    if (tid < 64) bsh[tid] = b2[tid];
    __syncthreads();

    // ---- GEMM2: relu(h1 @ W2 + b2) ----
#pragma unroll
    for (int i = 0; i < 4; ++i)
#pragma unroll
        for (int j = 0; j < 4; ++j) acc[i][j] = 0.f;
#pragma unroll 8
    for (int k = 0; k < 64; ++k) {
        float4 xv = *reinterpret_cast<const float4*>(&xs[k][r]);
        float4 wv = *reinterpret_cast<const float4*>(&wsh[k * 64 + c]);
        float xa[4] = {xv.x, xv.y, xv.z, xv.w};
        float wa[4] = {wv.x, wv.y, wv.z, wv.w};
#pragma unroll
        for (int i = 0; i < 4; ++i)
#pragma unroll
            for (int j = 0; j < 4; ++j) acc[i][j] = fmaf(xa[i], wa[j], acc[i][j]);
    }
    {
        float bj0 = bsh[c + 0], bj1 = bsh[c + 1], bj2 = bsh[c + 2], bj3 = bsh[c + 3];
#pragma unroll
        for (int i = 0; i < 4; ++i) {
            acc[i][0] = fmaxf(acc[i][0] + bj0, 0.f);
            acc[i][1] = fmaxf(acc[i][1] + bj1, 0.f);
            acc[i][2] = fmaxf(acc[i][2] + bj2, 0.f);
            acc[i][3] = fmaxf(acc[i][3] + bj3, 0.f);
        }
    }

    // store raw h (fp16) + BN stats
#pragma unroll
    for (int i = 0; i < 4; ++i) {
        int row = r0 + r + i;
        if (row < N_NODES) {
            union { float2 f; __half2 h[2]; } u;
            u.h[0] = __float22half2_rn(make_float2(acc[i][0], acc[i][1]));
            u.h[1] = __float22half2_rn(make_float2(acc[i][2], acc[i][3]));
            *reinterpret_cast<float2*>(hout + (size_t)row * 64 + c) = u.f;
        }
    }
#pragma unroll
    for (int j = 0; j < 4; ++j) {
        float s = 0.f, q = 0.f;
#pragma unroll
        for (int i = 0; i < 4; ++i) {
            if (r0 + r + i < N_NODES) {
                s += acc[i][j];
                q += acc[i][j] * acc[i][j];
            }
        }
        atomicAdd(&sred[c + j], s);
        atomicAdd(&sred[64 + c + j], q);
    }
    __syncthreads();
    if (tid < 128) atomicAdd(&stats[tid], sred[tid]);
}

// ---------------------------------------------------------------------------
// h' = relu(BN(h)) elementwise, fp16 -> fp16
__global__ __launch_bounds__(256) void bnrelu_k(const __half* hin,
                                                const float* __restrict__ stats,
                                                const float* __restrict__ g,
                                                const float* __restrict__ bt,
                                                __half* hout) {
    __shared__ float ssc[64], sof[64];
    int tid = threadIdx.x;
    if (tid < 64) {
        float mean = stats[tid] * (1.f / N_NODES);
        float var = stats[64 + tid] * (1.f / N_NODES) - mean * mean;
        float sc = g[tid] * rsqrtf(var + BN_EPS);
        ssc[tid] = sc;
        sof[tid] = bt[tid] - mean * sc;
    }
    __syncthreads();
    int gid = blockIdx.x * 256 + tid;      // one half8 (16 B) per thread
    if (gid >= N_NODES * 8) return;
    int c0 = (gid & 7) * 8;
    union { float4 f; __half2 h[4]; } u;
    u.f = reinterpret_cast<const float4*>(hin)[gid];
#pragma unroll
    for (int q = 0; q < 4; ++q) {
        float2 v = __half22float2(u.h[q]);
        v.x = fmaxf(fmaf(v.x, ssc[c0 + 2 * q], sof[c0 + 2 * q]), 0.f);
        v.y = fmaxf(fmaf(v.y, ssc[c0 + 2 * q + 1], sof[c0 + 2 * q + 1]), 0.f);
        u.h[q] = __float22half2_rn(v);
    }
    reinterpret_cast<float4*>(hout)[gid] = u.f;
}

// ---------------------------------------------------------------------------
// out[N x 16] = h' @ wl + bl   (h' fp16, already activated)
__global__ __launch_bounds__(256) void final_k(const __half* __restrict__ hin,
                                               const float* __restrict__ wl,
                                               const float* __restrict__ bl,
                                               float* __restrict__ out) {
    __shared__ float xs[64][68];
    __shared__ float wsh[64 * 16];
    __shared__ float bsh[16];
    int tid = threadIdx.x;
    int r0 = blockIdx.x * 64;

    reinterpret_cast<float4*>(wsh)[tid] = reinterpret_cast<const float4*>(wl)[tid];
    if (tid < 16) bsh[tid] = bl[tid];

    {
        int rr = tid >> 4, cg = tid & 15;
#pragma unroll
        for (int i = 0; i < 4; ++i) {
            int r = rr + i * 16;
            float4 v = make_float4(0.f, 0.f, 0.f, 0.f);
            if (r0 + r < N_NODES) {
                union { float2 f; __half2 h[2]; } u;
                u.f = reinterpret_cast<const float2*>(hin + (size_t)(r0 + r) * 64)[cg];
                float2 f0 = __half22float2(u.h[0]);
                float2 f1 = __half22float2(u.h[1]);
                v = make_float4(f0.x, f0.y, f1.x, f1.y);
            }
            xs[cg * 4 + 0][r] = v.x;
            xs[cg * 4 + 1][r] = v.y;
            xs[cg * 4 + 2][r] = v.z;
            xs[cg * 4 + 3][r] = v.w;
        }
    }
    __syncthreads();

    int tc = tid & 3, r = tid >> 2;
    int c = tc * 4;
    float acc0 = 0.f, acc1 = 0.f, acc2 = 0.f, acc3 = 0.f;
#pragma unroll 8
    for (int k = 0; k < 64; ++k) {
        float xv = xs[k][r];
        float4 wv = *reinterpret_cast<const float4*>(&wsh[k * 16 + c]);
        acc0 = fmaf(xv, wv.x, acc0);
        acc1 = fmaf(xv, wv.y, acc1);
        acc2 = fmaf(xv, wv.z, acc2);
        acc3 = fmaf(xv, wv.w, acc3);
    }
    int row = r0 + r;
    if (row < N_NODES) {
        float4 o = make_float4(acc0 + bsh[c], acc1 + bsh[c + 1], acc2 + bsh[c + 2], acc3 + bsh[c + 3]);
        *reinterpret_cast<float4*>(out + (size_t)row * 16 + c) = o;
    }
}

// ---------------------------------------------------------------------------
extern "C" void kernel_launch(void* const* d_in, const int* in_sizes, int n_in,
                              void* d_out, int out_size, void* d_ws, size_t ws_size,
                              hipStream_t stream) {
    const float* x = (const float*)d_in[0];
    const int* ei = (const int*)d_in[1];
    const int E = in_sizes[1] / 2;

    const float* eps[3] = {(const float*)d_in[2], (const float*)d_in[9], (const float*)d_in[16]};
    const float* w1[3]  = {(const float*)d_in[3], (const float*)d_in[10], (const float*)d_in[17]};
    const float* b1[3]  = {(const float*)d_in[4], (const float*)d_in[11], (const float*)d_in[18]};
    const float* w2[3]  = {(const float*)d_in[5], (const float*)d_in[12], (const float*)d_in[19]};
    const float* b2[3]  = {(const float*)d_in[6], (const float*)d_in[13], (const float*)d_in[20]};
    const float* g[3]   = {(const float*)d_in[7], (const float*)d_in[14], (const float*)d_in[21]};
    const float* bt[3]  = {(const float*)d_in[8], (const float*)d_in[15], (const float*)d_in[22]};
    const float* wl = (const float*)d_in[23];
    const float* bl = (const float*)d_in[24];

    // workspace layout
    __half* xh   = (__half*)d_ws;                       // N*64 fp16
    __half* ha   = xh + (size_t)N_NODES * 64;
    __half* hb   = ha + (size_t)N_NODES * 64;
    float* agg   = (float*)(hb + (size_t)N_NODES * 64); // N*64 fp32
    float* stats = agg + (size_t)N_NODES * 64;
    int* gcnt    = (int*)(stats + 384);
    int* bbase   = gcnt + NB;
    int* gcursor = bbase + (NB + 1);
    int* row_ptr = gcursor + NB;
    int* tail    = row_ptr + (N_NODES + 1);
    size_t used  = (size_t)((char*)tail - (char*)d_ws);

    int* csr_src = tail;                 // E ints, persists through all layers
    int* part;                           // E ints, build-only
    if (used + 2 * (size_t)E * 4 <= ws_size) {
        part = csr_src + E;
    } else {
        // d_out (N*16 f32 = E*4 bytes) as build-only scratch; consumed by
        // sortB_k long before final_k writes d_out.
        part = (int*)d_out;
    }

    const int n4 = N_NODES * 16;

    // ---- partition + CSR build + x->fp16 (once) ----
    zero_misc_k<<<(NB + 255) / 256, 256, 0, stream>>>(stats, gcnt);
    tofp16_k<<<(n4 + 255) / 256, 256, 0, stream>>>(x, xh, n4);
    histA_k<<<PART_BLOCKS, 256, 0, stream>>>(ei, gcnt, E);
    scanA_k<<<1, 256, 0, stream>>>(gcnt, bbase, gcursor);
    partA_k<<<PART_BLOCKS, 256, 0, stream>>>(ei, gcursor, part, E);
    sortB_k<<<NB, 256, 0, stream>>>(part, bbase, row_ptr, csr_src);

    const int gthblk = N_NODES / 16;              // 6250
    const int mlpblk = (N_NODES + 63) / 64;       // 1563
    const int bnblk  = (N_NODES * 8 + 255) / 256; // 3125

    // ---- layer 0 ----
    gather_k<<<gthblk, 256, 0, stream>>>(xh, row_ptr, csr_src, eps[0], agg);
    mlp_k<<<mlpblk, 256, 0, stream>>>(agg, w1[0], b1[0], w2[0], b2[0], ha, stats + 0);
    bnrelu_k<<<bnblk, 256, 0, stream>>>(ha, stats + 0, g[0], bt[0], ha);
    // ---- layer 1 ----
    gather_k<<<gthblk, 256, 0, stream>>>(ha, row_ptr, csr_src, eps[1], agg);
    mlp_k<<<mlpblk, 256, 0, stream>>>(agg, w1[1], b1[1], w2[1], b2[1], hb, stats + 128);
    bnrelu_k<<<bnblk, 256, 0, stream>>>(hb, stats + 128, g[1], bt[1], hb);
    // ---- layer 2 ----
    gather_k<<<gthblk, 256, 0, stream>>>(hb, row_ptr, csr_src, eps[2], agg);
    mlp_k<<<mlpblk, 256, 0, stream>>>(agg, w1[2], b1[2], w2[2], b2[2], ha, stats + 256);
    bnrelu_k<<<bnblk, 256, 0, stream>>>(ha, stats + 256, g[2], bt[2], ha);

    // ---- final linear ----
    final_k<<<(N_NODES + 63) / 64, 256, 0, stream>>>(ha, wl, bl, (float*)d_out);
}